// Round 1
// baseline (389.080 us; speedup 1.0000x reference)
//
#include <hip/hip_runtime.h>
#include <hip/hip_bf16.h>

// ---------------------------------------------------------------------------
// Direct 3x3 conv (pad=1) with fused bias+ReLU. Input may be a virtual concat
// of two tensors (CIN1 channels from in1, CIN2 from in2). One thread computes
// one output pixel for ALL COUT channels; weight loads are wave-uniform
// (scalar s_loads).
// ---------------------------------------------------------------------------
template <int CIN1, int CIN2, int COUT, int STRIDE>
__global__ __launch_bounds__(256) void conv3x3_k(
    const float* __restrict__ in1, const float* __restrict__ in2,
    const float* __restrict__ w,    // [COUT][CIN1+CIN2][3][3]
    const float* __restrict__ bias, // [COUT]
    float* __restrict__ out,
    int B, int Hin, int Win, int Hout, int Wout)
{
    constexpr int CIN = CIN1 + CIN2;
    int idx = blockIdx.x * 256 + threadIdx.x;
    int total = B * Hout * Wout;
    if (idx >= total) return;
    int x = idx % Wout;
    int y = (idx / Wout) % Hout;
    int b = idx / (Wout * Hout);

    float acc[COUT];
#pragma unroll
    for (int c = 0; c < COUT; ++c) acc[c] = bias[c];

    const int ybase = y * STRIDE - 1;
    const int xbase = x * STRIDE - 1;
    const int HW = Hin * Win;

#pragma unroll 1
    for (int ci = 0; ci < CIN; ++ci) {
        const float* src;
        if (CIN2 == 0 || ci < CIN1)
            src = in1 + (size_t)(b * CIN1 + ci) * HW;
        else
            src = in2 + (size_t)(b * CIN2 + (ci - CIN1)) * HW;

        float v[9];
#pragma unroll
        for (int ky = 0; ky < 3; ++ky) {
            int iy = ybase + ky;
            bool yok = (unsigned)iy < (unsigned)Hin;
#pragma unroll
            for (int kx = 0; kx < 3; ++kx) {
                int ix = xbase + kx;
                bool ok = yok && ((unsigned)ix < (unsigned)Win);
                v[ky * 3 + kx] = ok ? src[iy * Win + ix] : 0.0f;
            }
        }
#pragma unroll
        for (int c = 0; c < COUT; ++c) {
#pragma unroll
            for (int k = 0; k < 9; ++k)
                acc[c] += v[k] * w[(c * CIN + ci) * 9 + k];
        }
    }

    size_t obase = (size_t)b * COUT * Hout * Wout + (size_t)y * Wout + x;
#pragma unroll
    for (int c = 0; c < COUT; ++c)
        out[obase + (size_t)c * Hout * Wout] = fmaxf(acc[c], 0.0f);
}

// ---------------------------------------------------------------------------
// FC1: h[32,1024] = relu(xs[32,24576] @ fw1[1024,24576]^T + fb1)
// Stage kernel: split-K (32 chunks of 768), 64-n tile per block.
// LDS double-tile: As[k][m] (transposed xs), Bs[k][n] (transposed fw1 tile).
// Each thread computes a 4m x 2n micro-tile. fw1 read exactly once, coalesced.
// ---------------------------------------------------------------------------
#define FC1_K 24576
#define FC1_N 1024
#define FC1_M 32
#define FC1_KS 32   // k splits
#define FC1_KC 768  // k per split
#define FC1_KP 64   // k per phase
#define FC1_NT 64   // n per block

__global__ __launch_bounds__(256) void fc1_stage_k(
    const float* __restrict__ xs,   // [32][24576]
    const float* __restrict__ fw1,  // [1024][24576]
    float* __restrict__ part)       // [KS][32][1024]
{
    __shared__ __align__(16) float As[FC1_KP][36]; // [k][m], padded
    __shared__ __align__(16) float Bs[FC1_KP][66]; // [k][n], padded

    const int tid = threadIdx.x;
    const int n0 = blockIdx.x * FC1_NT;
    const int ks = blockIdx.y;
    const int k0 = ks * FC1_KC;
    const int lane = tid & 63;  // k index for loads
    const int grp = tid >> 6;   // 0..3

    const int mq = tid & 7;   // -> m4 = mq*4
    const int np = tid >> 3;  // 0..31 -> n2 = np*2
    const int m4 = mq * 4;
    const int n2 = np * 2;

    float acc[4][2];
#pragma unroll
    for (int i = 0; i < 4; ++i)
#pragma unroll
        for (int j = 0; j < 2; ++j) acc[i][j] = 0.0f;

    for (int p = 0; p < FC1_KC / FC1_KP; ++p) {
        const int kc = k0 + p * FC1_KP;
        // load xs tile (transposed): 8 rows per group
#pragma unroll
        for (int r = 0; r < 8; ++r) {
            int m = grp * 8 + r;
            As[lane][m] = xs[(size_t)m * FC1_K + kc + lane];
        }
        // load fw1 tile (transposed): 16 rows per group
#pragma unroll
        for (int r = 0; r < 16; ++r) {
            int nl = grp * 16 + r;
            Bs[lane][nl] = fw1[(size_t)(n0 + nl) * FC1_K + kc + lane];
        }
        __syncthreads();
#pragma unroll 8
        for (int k = 0; k < FC1_KP; ++k) {
            float4 a = *(const float4*)&As[k][m4];
            float2 bv = *(const float2*)&Bs[k][n2];
            acc[0][0] += a.x * bv.x; acc[0][1] += a.x * bv.y;
            acc[1][0] += a.y * bv.x; acc[1][1] += a.y * bv.y;
            acc[2][0] += a.z * bv.x; acc[2][1] += a.z * bv.y;
            acc[3][0] += a.w * bv.x; acc[3][1] += a.w * bv.y;
        }
        __syncthreads();
    }
#pragma unroll
    for (int i = 0; i < 4; ++i)
#pragma unroll
        for (int j = 0; j < 2; ++j)
            part[((size_t)ks * FC1_M + (m4 + i)) * FC1_N + n0 + n2 + j] = acc[i][j];
}

__global__ __launch_bounds__(256) void fc1_reduce_k(
    const float* __restrict__ part, const float* __restrict__ fb1,
    float* __restrict__ h1)
{
    int idx = blockIdx.x * 256 + threadIdx.x; // 32768
    int n = idx & (FC1_N - 1);
    int m = idx >> 10;
    float s = fb1[n];
#pragma unroll
    for (int ks = 0; ks < FC1_KS; ++ks)
        s += part[((size_t)ks * FC1_M + m) * FC1_N + n];
    h1[idx] = fmaxf(s, 0.0f);
}

// ---------------------------------------------------------------------------
// FC2: h2[32,32] = relu(h1[32,1024] @ fw2[32,1024]^T + fb2). One block per m.
// ---------------------------------------------------------------------------
__global__ __launch_bounds__(256) void fc2_k(
    const float* __restrict__ h1, const float* __restrict__ fw2,
    const float* __restrict__ fb2, float* __restrict__ h2)
{
    __shared__ float hs[1024];
    const int m = blockIdx.x;
    const int tid = threadIdx.x;
    for (int i = tid; i < 1024; i += 256) hs[i] = h1[m * 1024 + i];
    __syncthreads();
    const int wave = tid >> 6, lane = tid & 63;
#pragma unroll 1
    for (int nn = 0; nn < 8; ++nn) {
        int n = wave * 8 + nn;
        float p = 0.0f;
        for (int k = lane; k < 1024; k += 64)
            p += fw2[n * 1024 + k] * hs[k];
#pragma unroll
        for (int off = 32; off; off >>= 1) p += __shfl_xor(p, off);
        if (lane == 0) h2[m * 32 + n] = fmaxf(p + fb2[n], 0.0f);
    }
}

// ---------------------------------------------------------------------------
// FC3 + theta construction. 128 threads = 32 batches x 4 outputs.
// theta layout per batch: [a, 0, tx, 0, e, ty] (row-major 2x3).
// Written directly into d_out tail.
// ---------------------------------------------------------------------------
__global__ void fc3_theta_k(
    const float* __restrict__ h2, const float* __restrict__ fw3,
    const float* __restrict__ fb3, float* __restrict__ theta_out)
{
    int t = threadIdx.x;
    if (t >= 128) return;
    int m = t >> 2, j = t & 3;
    float s = fb3[j];
#pragma unroll
    for (int k = 0; k < 32; ++k) s += h2[m * 32 + k] * fw3[j * 32 + k];
    float* th = theta_out + m * 6;
    if (j == 0)      { th[0] = 1.0f / (1.0f + expf(-s)); th[1] = 0.0f; }
    else if (j == 1) { th[4] = 1.0f / (1.0f + expf(-s)); th[3] = 0.0f; }
    else if (j == 2) { th[2] = tanhf(s); }
    else             { th[5] = tanhf(s); }
}

// ---------------------------------------------------------------------------
// Bilinear grid-sample, padding_mode='zeros', align_corners=False. C=1.
// ---------------------------------------------------------------------------
__global__ __launch_bounds__(256) void sampler_k(
    const float* __restrict__ im, const float* __restrict__ theta,
    float* __restrict__ out)
{
    int idx = blockIdx.x * 256 + threadIdx.x; // b*65536 + y*256 + x
    int x = idx & 255;
    int y = (idx >> 8) & 255;
    int b = idx >> 16;
    const float* th = theta + b * 6;
    float xsn = (2.0f * x + 1.0f) * (1.0f / 256.0f) - 1.0f;
    float ysn = (2.0f * y + 1.0f) * (1.0f / 256.0f) - 1.0f;
    float gx = th[0] * xsn + th[1] * ysn + th[2];
    float gy = th[3] * xsn + th[4] * ysn + th[5];
    float ix = ((gx + 1.0f) * 256.0f - 1.0f) * 0.5f;
    float iy = ((gy + 1.0f) * 256.0f - 1.0f) * 0.5f;
    float x0 = floorf(ix), y0 = floorf(iy);
    float wx1 = ix - x0, wy1 = iy - y0;
    float wx0 = 1.0f - wx1, wy0 = 1.0f - wy1;
    const float* src = im + (size_t)b * 65536;

    auto g = [&](float xf, float yf) -> float {
        if (xf < 0.0f || xf > 255.0f || yf < 0.0f || yf > 255.0f) return 0.0f;
        int xi = (int)xf, yi = (int)yf;
        return src[yi * 256 + xi];
    };
    float v00 = g(x0, y0);
    float v10 = g(x0 + 1.0f, y0);
    float v01 = g(x0, y0 + 1.0f);
    float v11 = g(x0 + 1.0f, y0 + 1.0f);
    out[idx] = v00 * wx0 * wy0 + v10 * wx1 * wy0 + v01 * wx0 * wy1 + v11 * wx1 * wy1;
}

// ---------------------------------------------------------------------------
// Launch. Workspace layout (floats), peak 64 MB:
//   x1c  [0,        4194304)   conv1 output for an 8-batch chunk
//   x2   [4194304,  8388608)   32x8x128x128
//   x3   [8388608, 16777216)   32x16x128x128
//   x4   [0,        2097152)   32x16x64x64   (x1c dead)
//   x5   [2097152,  5242880)   32x24x64x64   (x2 dead after conv4... written by conv5)
//   x6   [5242880,  6029312)   32x24x32x32
//   part [6029312,  7077888)   32x32x1024 split-K partials (x3 dead)
//   h1   [7077888,  7110656)
//   h2   [7110656,  7111680)
// ---------------------------------------------------------------------------
extern "C" void kernel_launch(void* const* d_in, const int* in_sizes, int n_in,
                              void* d_out, int out_size, void* d_ws, size_t ws_size,
                              hipStream_t stream)
{
    const float* im  = (const float*)d_in[0];
    const float* w1  = (const float*)d_in[1];  const float* b1 = (const float*)d_in[2];
    const float* w2  = (const float*)d_in[3];  const float* b2 = (const float*)d_in[4];
    const float* w3  = (const float*)d_in[5];  const float* b3 = (const float*)d_in[6];
    const float* w4  = (const float*)d_in[7];  const float* b4 = (const float*)d_in[8];
    const float* w5  = (const float*)d_in[9];  const float* b5 = (const float*)d_in[10];
    const float* w6  = (const float*)d_in[11]; const float* b6 = (const float*)d_in[12];
    const float* fw1 = (const float*)d_in[13]; const float* fb1 = (const float*)d_in[14];
    const float* fw2 = (const float*)d_in[15]; const float* fb2 = (const float*)d_in[16];
    const float* fw3 = (const float*)d_in[17]; const float* fb3 = (const float*)d_in[18];

    float* out = (float*)d_out;
    float* ws  = (float*)d_ws;

    float* x1c  = ws + 0;
    float* x2   = ws + 4194304;
    float* x3   = ws + 8388608;
    float* x4   = ws + 0;
    float* x5   = ws + 2097152;
    float* x6   = ws + 5242880;
    float* part = ws + 6029312;
    float* h1   = ws + 7077888;
    float* h2   = ws + 7110656;

    float* theta = out + 32 * 65536; // theta tail of d_out

    // conv1 + conv2, chunked over batch (8 at a time) to bound workspace
    for (int c = 0; c < 4; ++c) {
        const float* imc = im + (size_t)c * 8 * 65536;
        conv3x3_k<1, 0, 8, 1><<<2048, 256, 0, stream>>>(
            imc, nullptr, w1, b1, x1c, 8, 256, 256, 256, 256);
        conv3x3_k<8, 1, 8, 2><<<512, 256, 0, stream>>>(
            x1c, imc, w2, b2, x2 + (size_t)c * 1048576, 8, 256, 256, 128, 128);
    }
    conv3x3_k<8, 0, 16, 1><<<2048, 256, 0, stream>>>(
        x2, nullptr, w3, b3, x3, 32, 128, 128, 128, 128);
    conv3x3_k<16, 8, 16, 2><<<512, 256, 0, stream>>>(
        x3, x2, w4, b4, x4, 32, 128, 128, 64, 64);
    conv3x3_k<16, 0, 24, 1><<<512, 256, 0, stream>>>(
        x4, nullptr, w5, b5, x5, 32, 64, 64, 64, 64);
    conv3x3_k<24, 16, 24, 2><<<128, 256, 0, stream>>>(
        x5, x4, w6, b6, x6, 32, 64, 64, 32, 32);

    // FC stack
    fc1_stage_k<<<dim3(16, FC1_KS), 256, 0, stream>>>(x6, fw1, part);
    fc1_reduce_k<<<128, 256, 0, stream>>>(part, fb1, h1);
    fc2_k<<<32, 256, 0, stream>>>(h1, fw2, fb2, h2);
    fc3_theta_k<<<1, 128, 0, stream>>>(h2, fw3, fb3, theta);

    // grid sample from theta (written into d_out tail, stream-ordered)
    sampler_k<<<8192, 256, 0, stream>>>(im, theta, out);
}